// Round 6
// baseline (2663.289 us; speedup 1.0000x reference)
//
#include <hip/hip_runtime.h>

#define Bn 8
#define Nn 8192
#define Cn 64
#define Mn 2048
#define Kn 16
#define FPS_T 256
#define PPT (Nn / FPS_T)     // 32 points/thread
#define NPAIR (PPT / 2)      // 16 packed pairs/thread
#define NWAVE (FPS_T / 64)   // 4 waves

typedef float f32x2 __attribute__((ext_vector_type(2)));
typedef unsigned long long u64;

// ---- DPP wave-64 reductions (rocPRIM gfx9 pattern), result valid in lane 63.
template <int CTRL, int RMASK>
__device__ __forceinline__ float dpp_max_step(float v) {
    int mv = __builtin_amdgcn_update_dpp(__float_as_int(v), __float_as_int(v),
                                         CTRL, RMASK, 0xF, false);
    return fmaxf(v, __int_as_float(mv));
}
template <int CTRL, int RMASK>
__device__ __forceinline__ unsigned dpp_min_step(unsigned v) {
    unsigned mv = (unsigned)__builtin_amdgcn_update_dpp((int)v, (int)v,
                                                        CTRL, RMASK, 0xF, false);
    return (mv < v) ? mv : v;
}
__device__ __forceinline__ float wave_max_f32(float v) {
    v = dpp_max_step<0x111, 0xF>(v);   // row_shr:1
    v = dpp_max_step<0x112, 0xF>(v);   // row_shr:2
    v = dpp_max_step<0x114, 0xF>(v);   // row_shr:4
    v = dpp_max_step<0x118, 0xF>(v);   // row_shr:8
    v = dpp_max_step<0x142, 0xA>(v);   // row_bcast:15
    v = dpp_max_step<0x143, 0xC>(v);   // row_bcast:31
    return v;                           // lane 63 holds the wave max
}
__device__ __forceinline__ unsigned wave_min_u32(unsigned v) {
    v = dpp_min_step<0x111, 0xF>(v);
    v = dpp_min_step<0x112, 0xF>(v);
    v = dpp_min_step<0x114, 0xF>(v);
    v = dpp_min_step<0x118, 0xF>(v);
    v = dpp_min_step<0x142, 0xA>(v);
    v = dpp_min_step<0x143, 0xC>(v);
    return v;                           // lane 63 holds the wave min
}
__device__ __forceinline__ u64 u64max(u64 a, u64 b) { return a > b ? a : b; }

// ---------------------------------------------------------------------------
// FPS: one block/batch, 256 threads (4 waves, 1/SIMD), 32 pts/thread in
// registers as 16 pairs. Packed dual-FP32 distance via inline-asm VOP3P
// (v_pk_add_f32 / v_pk_mul_f32) -- bit-identical rounding to scalar rn ops.
// One barrier/iter; cross-wave argmax via 4 packed (Vbits<<32 | ~idx) keys
// in double-buffered LDS, register-combined by every thread.
// ---------------------------------------------------------------------------
__global__ __launch_bounds__(FPS_T, 1) void fps_kernel(
    const float* __restrict__ p1,
    float* __restrict__ out_p2,
    float* __restrict__ out_idxf)
{
    __shared__ float s_Px[Nn], s_Py[Nn], s_Pz[Nn];      // 96 KB
    __shared__ u64 s_wkey[2][NWAVE];
    __shared__ int s_oidx[Mn];                           // 8 KB

    const int b = blockIdx.x;
    const int t = threadIdx.x;
    const int w = t >> 6;
    const float* __restrict__ P = p1 + (size_t)b * (Nn * 3);

    f32x2 px2[NPAIR], py2[NPAIR], pz2[NPAIR];
    float d2lo[NPAIR], d2hi[NPAIR];
#pragma unroll
    for (int j = 0; j < PPT; ++j) {
        const int g = t + j * FPS_T;
        const float x = P[g * 3 + 0];
        const float y = P[g * 3 + 1];
        const float z = P[g * 3 + 2];
        const int k = j >> 1;
        if ((j & 1) == 0) { px2[k].x = x; py2[k].x = y; pz2[k].x = z; }
        else              { px2[k].y = x; py2[k].y = y; pz2[k].y = z; }
        s_Px[g] = x; s_Py[g] = y; s_Pz[g] = z;
    }
#pragma unroll
    for (int k = 0; k < NPAIR; ++k) {
        d2lo[k] = __int_as_float(0x7f800000);
        d2hi[k] = __int_as_float(0x7f800000);
    }
    if (t == 0) s_oidx[0] = 0;
    __syncthreads();

    float qx = s_Px[0], qy = s_Py[0], qz = s_Pz[0];

    for (int m = 1; m < Mn; ++m) {
        // ---- packed exact distance update + per-thread max ----
        const f32x2 nqx = { -qx, -qx };
        const f32x2 nqy = { -qy, -qy };
        const f32x2 nqz = { -qz, -qz };
        float lm = -1.0f;
#pragma unroll
        for (int k = 0; k < NPAIR; ++k) {
            f32x2 s, t1, t2;
            // dx=p+(-q); squares; (x^2+y^2)+z^2 -- rn at every step, no FMA.
            asm("v_pk_add_f32 %0, %3, %6\n\t"
                "v_pk_add_f32 %1, %4, %7\n\t"
                "v_pk_add_f32 %2, %5, %8\n\t"
                "v_pk_mul_f32 %0, %0, %0\n\t"
                "v_pk_mul_f32 %1, %1, %1\n\t"
                "v_pk_mul_f32 %2, %2, %2\n\t"
                "v_pk_add_f32 %0, %0, %1\n\t"
                "v_pk_add_f32 %0, %0, %2"
                : "=&v"(s), "=&v"(t1), "=&v"(t2)
                : "v"(px2[k]), "v"(py2[k]), "v"(pz2[k]),
                  "v"(nqx), "v"(nqy), "v"(nqz));
            const float nlo = fminf(d2lo[k], s.x);
            const float nhi = fminf(d2hi[k], s.y);
            d2lo[k] = nlo;
            d2hi[k] = nhi;
            lm = fmaxf(lm, fmaxf(nlo, nhi));   // -> v_max3_f32
        }
        // ---- wave max value ----
        const float wv = wave_max_f32(lm);
        const float V = __int_as_float(
            __builtin_amdgcn_readlane(__float_as_int(wv), 63));
        // ---- first (smallest) index matching V; only owning threads scan ----
        unsigned cand = 0xFFFFFFFFu;
        if (lm == V) {
#pragma unroll
            for (int k = NPAIR - 1; k >= 0; --k) {     // descending g order
                const unsigned ghi = (unsigned)(t + (2 * k + 1) * FPS_T);
                const unsigned glo = (unsigned)(t + (2 * k) * FPS_T);
                cand = (d2hi[k] == V) ? ghi : cand;
                cand = (d2lo[k] == V) ? glo : cand;
            }
        }
        cand = wave_min_u32(cand);
        // ---- publish per-wave key; double-buffered slots, one barrier ----
        if ((t & 63) == 63) {
            const u64 key = ((u64)(unsigned)__float_as_int(V) << 32) |
                            (u64)(~cand);
            s_wkey[m & 1][w] = key;
        }
        __syncthreads();
        const u64* __restrict__ K = s_wkey[m & 1];
        const u64 kk = u64max(u64max(K[0], K[1]), u64max(K[2], K[3]));
        const int bi = (int)(~(unsigned)kk);
        if (t == 0) s_oidx[m] = bi;
        qx = s_Px[bi]; qy = s_Py[bi]; qz = s_Pz[bi];   // broadcast LDS reads
    }
    __syncthreads();

    // ---- flush outputs ----
    float* __restrict__ o2 = out_p2 + (size_t)b * Mn * 3;
    float* __restrict__ oi = out_idxf + (size_t)b * Mn;
    for (int i = t; i < Mn; i += FPS_T) {
        const int bi = s_oidx[i];
        oi[i] = (float)bi;
        o2[i * 3 + 0] = s_Px[bi];
        o2[i * 3 + 1] = s_Py[bi];
        o2[i * 3 + 2] = s_Pz[bi];
    }
}

// ---------------------------------------------------------------------------
// kNN + feature mean (unchanged -- passed rounds 1/4/5).
// ---------------------------------------------------------------------------
#define KNN_WPB 4
__global__ __launch_bounds__(64 * KNN_WPB) void knn_mean_kernel(
    const float* __restrict__ p1,
    const float* __restrict__ x,
    const float* __restrict__ p2,
    float* __restrict__ y)
{
    const int lane = threadIdx.x & 63;
    const int wid  = threadIdx.x >> 6;
    const int q    = blockIdx.x * KNN_WPB + wid;    // 0 .. B*M-1
    const int b    = q >> 11;                        // q / Mn  (Mn = 2048)
    const float* __restrict__ P = p1 + (size_t)b * (Nn * 3);

    const float qx = p2[(size_t)q * 3 + 0];
    const float qy = p2[(size_t)q * 3 + 1];
    const float qz = p2[(size_t)q * 3 + 2];
    const float qq = __fadd_rn(
        __fadd_rn(__fmul_rn(qx, qx), __fmul_rn(qy, qy)), __fmul_rn(qz, qz));

    float slotv = __int_as_float(0x7f800000);
    int   sloti = 0x7fffffff;
    float thr   = __int_as_float(0x7f800000);
    int   thri  = 0x7fffffff;

    for (int c = 0; c < Nn / 64; ++c) {
        const int g = c * 64 + lane;
        const float ax = P[g * 3 + 0];
        const float ay = P[g * 3 + 1];
        const float az = P[g * 3 + 2];
        const float pp = __fadd_rn(
            __fadd_rn(__fmul_rn(ax, ax), __fmul_rn(ay, ay)), __fmul_rn(az, az));
        const float dot = __fmaf_rn(az, qz, __fmaf_rn(ay, qy, __fmul_rn(ax, qx)));
        const float d = __fsub_rn(__fadd_rn(qq, pp), __fmul_rn(2.0f, dot));
        const bool pass = (d < thr) || (d == thr && g < thri);
        unsigned long long ball = __ballot(pass);
        while (ball) {
            const int src = __builtin_ctzll(ball);
            ball &= ball - 1ull;
            const float v  = __shfl(d, src);
            const int   vi = __shfl(g, src);
            const float upv = __shfl_up(slotv, 1);
            const int   upi = __shfl_up(sloti, 1);
            const bool beforeme = (v < slotv) || (v == slotv && vi < sloti);
            bool beforeup = (v < upv) || (v == upv && vi < upi);
            if (lane == 0) beforeup = false;
            if (beforeme) {
                slotv = beforeup ? upv : v;
                sloti = beforeup ? upi : vi;
            }
            thr  = __shfl(slotv, 15);
            thri = __shfl(sloti, 15);
        }
    }

    float acc = 0.0f;
    const float* __restrict__ xb = x + (size_t)b * Nn * Cn;
#pragma unroll
    for (int s = 0; s < Kn; ++s) {
        const int ni = __shfl(sloti, s);
        acc = __fadd_rn(acc, xb[(size_t)ni * Cn + lane]);   // lane == channel
    }
    y[(size_t)q * Cn + lane] = __fmul_rn(acc, 0.0625f);
}

// ---------------------------------------------------------------------------
extern "C" void kernel_launch(void* const* d_in, const int* in_sizes, int n_in,
                              void* d_out, int out_size, void* d_ws, size_t ws_size,
                              hipStream_t stream) {
    const float* p1 = (const float*)d_in[0];
    const float* x  = (const float*)d_in[1];

    float* y    = (float*)d_out;                       // (B, M, C)
    float* p2   = y    + (size_t)Bn * Mn * Cn;         // (B, M, 3)
    float* idxf = p2   + (size_t)Bn * Mn * 3;          // (B, M) as float

    fps_kernel<<<Bn, FPS_T, 0, stream>>>(p1, p2, idxf);
    knn_mean_kernel<<<(Bn * Mn) / KNN_WPB, 64 * KNN_WPB, 0, stream>>>(p1, x, p2, y);
}

// Round 7
// 2102.488 us; speedup vs baseline: 1.2667x; 1.2667x over previous
//
#include <hip/hip_runtime.h>

#define Bn 8
#define Nn 8192
#define Cn 64
#define Mn 2048
#define Kn 16
#define FPS_T 512
#define CPT 16                   // points per thread chunk (sorted, contiguous)
#define NWAVE (FPS_T / 64)       // 8
#define NCELL 4096               // 16x16x16 Morton grid
#define CELLS_PT (NCELL / FPS_T) // 8

typedef unsigned long long u64;
typedef unsigned u32;

__device__ __forceinline__ u64 u64max(u64 a, u64 b) { return a > b ? a : b; }

// ---- fused u64 (value,index) DPP max step: both halves move with the same
// control; inactive lanes keep old (old==operand). Result in lane 63.
template <int CTRL, int RMASK>
__device__ __forceinline__ void dpp_kmax_step(u32& hi, u32& lo) {
    const u32 h2 = (u32)__builtin_amdgcn_update_dpp((int)hi, (int)hi, CTRL, RMASK, 0xF, false);
    const u32 l2 = (u32)__builtin_amdgcn_update_dpp((int)lo, (int)lo, CTRL, RMASK, 0xF, false);
    const u64 a = ((u64)hi << 32) | lo;
    const u64 bb = ((u64)h2 << 32) | l2;
    if (bb > a) { hi = h2; lo = l2; }
}
__device__ __forceinline__ void wave_kmax(u32& hi, u32& lo) {
    dpp_kmax_step<0x111, 0xF>(hi, lo);   // row_shr:1
    dpp_kmax_step<0x112, 0xF>(hi, lo);   // row_shr:2
    dpp_kmax_step<0x114, 0xF>(hi, lo);   // row_shr:4
    dpp_kmax_step<0x118, 0xF>(hi, lo);   // row_shr:8
    dpp_kmax_step<0x142, 0xA>(hi, lo);   // row_bcast:15
    dpp_kmax_step<0x143, 0xC>(hi, lo);   // row_bcast:31
}

__device__ __forceinline__ u32 spread4(u32 x) {   // 4 bits -> bits 0,3,6,9
    return (x & 1u) | ((x & 2u) << 2) | ((x & 4u) << 4) | ((x & 8u) << 6);
}
__device__ __forceinline__ u32 quant16(float v) {
    int c = (int)((v + 4.0f) * 2.0f);
    c = c < 0 ? 0 : (c > 15 ? 15 : c);
    return (u32)c;
}

// ---------------------------------------------------------------------------
// FPS with conservative chunk-skip. One block/batch, 512 threads (8 waves,
// 2/SIMD). Points Morton-sorted once (LDS counting sort); each thread owns 16
// contiguous sorted points + exact bbox. Per iter: if margin-adjusted
// dist(q,bbox)^2 >= cached chunk max d2, skip (provably no d2 change at
// reference rounding); else recompute chunk exactly (XLA-identical rn ops).
// Argmax via u64 key (d2bits<<32 | ~g<<19 | pos<<6): max value, then min
// original index g -- exact first-index tie-break end to end.
// ---------------------------------------------------------------------------
__global__ __launch_bounds__(FPS_T, 2) void fps_kernel(
    const float* __restrict__ p1,
    float* __restrict__ out_p2,
    float* __restrict__ out_idxf)
{
    __shared__ float s_Px[Nn], s_Py[Nn], s_Pz[Nn];   // 96 KB (sorted order)
    __shared__ u32 s_G[Nn];                           // 32 KB sorted->orig idx
    __shared__ u32 s_osel[Mn];                        // 8 KB (g<<13)|pos
    __shared__ int s_hist[NCELL];                     // 16 KB
    __shared__ int s_scan[FPS_T];                     // 2 KB
    __shared__ u64 s_wkey[2][NWAVE];

    const int b = blockIdx.x;
    const int t = threadIdx.x;
    const int w = t >> 6;
    const float* __restrict__ P = p1 + (size_t)b * (Nn * 3);

    float qx = P[0], qy = P[1], qz = P[2];

    // ---- load + quantize (unsorted ownership g = t + j*FPS_T) ----
    float rx[CPT], ry[CPT], rz[CPT];
    u32 cc[CPT];
#pragma unroll
    for (int j = 0; j < CPT; ++j) {
        const int g = t + j * FPS_T;
        rx[j] = P[g * 3 + 0];
        ry[j] = P[g * 3 + 1];
        rz[j] = P[g * 3 + 2];
        cc[j] = spread4(quant16(rx[j])) | (spread4(quant16(ry[j])) << 1) |
                (spread4(quant16(rz[j])) << 2);
    }
#pragma unroll
    for (int i = 0; i < CELLS_PT; ++i) s_hist[t * CELLS_PT + i] = 0;
    __syncthreads();
#pragma unroll
    for (int j = 0; j < CPT; ++j) atomicAdd(&s_hist[cc[j]], 1);
    __syncthreads();

    // ---- exclusive prefix over 4096 cells (8 serial/thread + block scan) ----
    int local[CELLS_PT];
    int sum = 0;
#pragma unroll
    for (int i = 0; i < CELLS_PT; ++i) { local[i] = s_hist[t * CELLS_PT + i]; sum += local[i]; }
    s_scan[t] = sum;
    __syncthreads();
    for (int off = 1; off < FPS_T; off <<= 1) {
        const int add = (t >= off) ? s_scan[t - off] : 0;
        __syncthreads();
        s_scan[t] += add;
        __syncthreads();
    }
    int base = s_scan[t] - sum;
#pragma unroll
    for (int i = 0; i < CELLS_PT; ++i) { s_hist[t * CELLS_PT + i] = base; base += local[i]; }
    __syncthreads();

    // ---- scatter into sorted order ----
#pragma unroll
    for (int j = 0; j < CPT; ++j) {
        const int g = t + j * FPS_T;
        const int pos = atomicAdd(&s_hist[cc[j]], 1);
        s_Px[pos] = rx[j]; s_Py[pos] = ry[j]; s_Pz[pos] = rz[j];
        s_G[pos] = (u32)g;
        if (g == 0) s_osel[0] = (u32)pos;   // (0<<13)|pos
    }
    __syncthreads();

    // ---- load my chunk (sorted positions t*16 .. t*16+15) + bbox ----
    float px[CPT], py[CPT], pz[CPT], d2[CPT];
    u32 gg[CPT];
    float lox, hix, loy, hiy, loz, hiz;
#pragma unroll
    for (int j = 0; j < CPT; ++j) {
        const int pos = t * CPT + j;
        const float x = s_Px[pos], y = s_Py[pos], z = s_Pz[pos];
        px[j] = x; py[j] = y; pz[j] = z;
        gg[j] = s_G[pos];
        d2[j] = __int_as_float(0x7f800000);
        if (j == 0) { lox = hix = x; loy = hiy = y; loz = hiz = z; }
        else {
            lox = fminf(lox, x); hix = fmaxf(hix, x);
            loy = fminf(loy, y); hiy = fmaxf(hiy, y);
            loz = fminf(loz, z); hiz = fmaxf(hiz, z);
        }
    }
    u32 ubhi = 0x7f800000u, ublo = 0u;   // cached chunk-argmax key (inf: force first update)

    for (int m = 1; m < Mn; ++m) {
        // ---- conservative skip test ----
        const float ddx = fmaxf(fmaxf(__fsub_rn(lox, qx), __fsub_rn(qx, hix)), 0.0f);
        const float ddy = fmaxf(fmaxf(__fsub_rn(loy, qy), __fsub_rn(qy, hiy)), 0.0f);
        const float ddz = fmaxf(fmaxf(__fsub_rn(loz, qz), __fsub_rn(qz, hiz)), 0.0f);
        const float Dmin2 = __fadd_rn(
            __fadd_rn(__fmul_rn(ddx, ddx), __fmul_rn(ddy, ddy)), __fmul_rn(ddz, ddz));
        const float S = __fmul_rn(Dmin2, 0.99999f);
        if (S < __uint_as_float(ubhi)) {
            // ---- exact chunk update (XLA-identical arithmetic) ----
            u32 bh = 0u, bl = 0u;
#pragma unroll
            for (int j = 0; j < CPT; ++j) {
                const float dx = __fsub_rn(px[j], qx);
                const float dy = __fsub_rn(py[j], qy);
                const float dz = __fsub_rn(pz[j], qz);
                const float dist = __fadd_rn(
                    __fadd_rn(__fmul_rn(dx, dx), __fmul_rn(dy, dy)),
                    __fmul_rn(dz, dz));
                const float nd = fminf(d2[j], dist);
                d2[j] = nd;
                const u32 kh = __float_as_uint(nd);
                const u32 kl = ((~gg[j] & 0x1FFFu) << 19) | ((u32)(t * CPT + j) << 6);
                const u64 cand = ((u64)kh << 32) | kl;
                if (cand > (((u64)bh << 32) | bl)) { bh = kh; bl = kl; }
            }
            ubhi = bh; ublo = bl;
        }
        // ---- wave + cross-wave argmax on cached keys ----
        u32 rh = ubhi, rl = ublo;
        wave_kmax(rh, rl);
        if ((t & 63) == 63) s_wkey[m & 1][w] = ((u64)rh << 32) | rl;
        __syncthreads();
        const u64* __restrict__ K = s_wkey[m & 1];
        const u64 kk = u64max(u64max(u64max(K[0], K[1]), u64max(K[2], K[3])),
                              u64max(u64max(K[4], K[5]), u64max(K[6], K[7])));
        const u32 pos = (u32)(kk >> 6) & 0x1FFFu;
        if (t == 0) {
            const u32 g = (~(u32)(kk >> 19)) & 0x1FFFu;
            s_osel[m] = (g << 13) | pos;
        }
        qx = s_Px[pos]; qy = s_Py[pos]; qz = s_Pz[pos];   // broadcast reads
    }
    __syncthreads();

    // ---- flush outputs ----
    float* __restrict__ o2 = out_p2 + (size_t)b * Mn * 3;
    float* __restrict__ oi = out_idxf + (size_t)b * Mn;
    for (int i = t; i < Mn; i += FPS_T) {
        const u32 sel = s_osel[i];
        const u32 pos = sel & 0x1FFFu;
        const u32 g = sel >> 13;
        oi[i] = (float)g;
        o2[i * 3 + 0] = s_Px[pos];
        o2[i * 3 + 1] = s_Py[pos];
        o2[i * 3 + 2] = s_Pz[pos];
    }
}

// ---------------------------------------------------------------------------
// kNN + feature mean (unchanged -- passed rounds 1/4/5/6).
// ---------------------------------------------------------------------------
#define KNN_WPB 4
__global__ __launch_bounds__(64 * KNN_WPB) void knn_mean_kernel(
    const float* __restrict__ p1,
    const float* __restrict__ x,
    const float* __restrict__ p2,
    float* __restrict__ y)
{
    const int lane = threadIdx.x & 63;
    const int wid  = threadIdx.x >> 6;
    const int q    = blockIdx.x * KNN_WPB + wid;    // 0 .. B*M-1
    const int b    = q >> 11;                        // q / Mn  (Mn = 2048)
    const float* __restrict__ P = p1 + (size_t)b * (Nn * 3);

    const float qx = p2[(size_t)q * 3 + 0];
    const float qy = p2[(size_t)q * 3 + 1];
    const float qz = p2[(size_t)q * 3 + 2];
    const float qq = __fadd_rn(
        __fadd_rn(__fmul_rn(qx, qx), __fmul_rn(qy, qy)), __fmul_rn(qz, qz));

    float slotv = __int_as_float(0x7f800000);
    int   sloti = 0x7fffffff;
    float thr   = __int_as_float(0x7f800000);
    int   thri  = 0x7fffffff;

    for (int c = 0; c < Nn / 64; ++c) {
        const int g = c * 64 + lane;
        const float ax = P[g * 3 + 0];
        const float ay = P[g * 3 + 1];
        const float az = P[g * 3 + 2];
        const float pp = __fadd_rn(
            __fadd_rn(__fmul_rn(ax, ax), __fmul_rn(ay, ay)), __fmul_rn(az, az));
        const float dot = __fmaf_rn(az, qz, __fmaf_rn(ay, qy, __fmul_rn(ax, qx)));
        const float d = __fsub_rn(__fadd_rn(qq, pp), __fmul_rn(2.0f, dot));
        const bool pass = (d < thr) || (d == thr && g < thri);
        unsigned long long ball = __ballot(pass);
        while (ball) {
            const int src = __builtin_ctzll(ball);
            ball &= ball - 1ull;
            const float v  = __shfl(d, src);
            const int   vi = __shfl(g, src);
            const float upv = __shfl_up(slotv, 1);
            const int   upi = __shfl_up(sloti, 1);
            const bool beforeme = (v < slotv) || (v == slotv && vi < sloti);
            bool beforeup = (v < upv) || (v == upv && vi < upi);
            if (lane == 0) beforeup = false;
            if (beforeme) {
                slotv = beforeup ? upv : v;
                sloti = beforeup ? upi : vi;
            }
            thr  = __shfl(slotv, 15);
            thri = __shfl(sloti, 15);
        }
    }

    float acc = 0.0f;
    const float* __restrict__ xb = x + (size_t)b * Nn * Cn;
#pragma unroll
    for (int s = 0; s < Kn; ++s) {
        const int ni = __shfl(sloti, s);
        acc = __fadd_rn(acc, xb[(size_t)ni * Cn + lane]);   // lane == channel
    }
    y[(size_t)q * Cn + lane] = __fmul_rn(acc, 0.0625f);
}

// ---------------------------------------------------------------------------
extern "C" void kernel_launch(void* const* d_in, const int* in_sizes, int n_in,
                              void* d_out, int out_size, void* d_ws, size_t ws_size,
                              hipStream_t stream) {
    const float* p1 = (const float*)d_in[0];
    const float* x  = (const float*)d_in[1];

    float* y    = (float*)d_out;                       // (B, M, C)
    float* p2   = y    + (size_t)Bn * Mn * Cn;         // (B, M, 3)
    float* idxf = p2   + (size_t)Bn * Mn * 3;          // (B, M) as float

    fps_kernel<<<Bn, FPS_T, 0, stream>>>(p1, p2, idxf);
    knn_mean_kernel<<<(Bn * Mn) / KNN_WPB, 64 * KNN_WPB, 0, stream>>>(p1, x, p2, y);
}